// Round 5
// baseline (309.586 us; speedup 1.0000x reference)
//
#include <hip/hip_runtime.h>

#define N_ROWS 4096
#define IN_F   4096
#define OUT_F  4096
#define C_CB   256
#define KDIM   4096   // C_CB * 16

typedef short bf16x8 __attribute__((ext_vector_type(8)));
typedef float f32x4  __attribute__((ext_vector_type(4)));

union ABFrag { unsigned long long u[2]; bf16x8 v; };

__device__ __forceinline__ unsigned int f2bf(float f) {
    unsigned int u = __builtin_bit_cast(unsigned int, f);
    return (u + 0x7FFFu + ((u >> 16) & 1u)) >> 16;   // RNE
}

// ---------------- Kernel 1: tree descent, task-parallel rewrite ----------------
// Old: one block per row (4096 tiny blocks, 35KB LDS, byte stores at 4096-stride,
// one dependent descent chain per thread). New: thread = (codebook c, 4 rows):
//  - dims/thr fetched once per thread; thr gathered from a 15KB LDS tile
//  - 16 independent row-gathers per thread (4 rows x 4 levels, chains overlap)
//  - stores coalesce to one dword (4 packed idx bytes) per even lane: 16x fewer
//    and no partial-line RMW sharing across blocks
#define IROWS 4
__global__ __launch_bounds__(256) void k_idx(const float* __restrict__ input,
                                             const int* __restrict__ dims,
                                             const float* __restrict__ thr,
                                             unsigned char* __restrict__ idx4) {
    __shared__ float thrS[C_CB * 15];    // 15 KB
    const int t  = threadIdx.x;
    const int n0 = blockIdx.x * IROWS;

    #pragma unroll
    for (int i = 0; i < 15; i++) thrS[i * 256 + t] = thr[i * 256 + t];
    __syncthreads();

    const int c = t;
    int4 d = *(const int4*)(dims + c * 4);
    const float* th = thrS + c * 15;

    unsigned int pack = 0;
    #pragma unroll
    for (int r = 0; r < IROWS; r++) {
        const float* row = input + (size_t)(n0 + r) * IN_F;
        float x0 = row[d.x], x1 = row[d.y], x2 = row[d.z], x3 = row[d.w];
        int b0 = x0 > th[0];
        int j1 = 1 + b0;
        int b1 = x1 > th[j1];
        int j2 = 2 * j1 + 1 + b1;
        int b2 = x2 > th[j2];
        int j3 = 2 * j2 + 1 + b2;
        int b3 = x3 > th[j3];
        unsigned int idx = (b0 << 3) | (b1 << 2) | (b2 << 1) | b3;
        pack |= idx << (8 * r);
    }
    // combine even/odd codebooks: each byte holds values <= 0xF, so <<4 stays in-byte
    unsigned int other = __shfl_xor(pack, 1);
    if (!(c & 1))
        *(unsigned int*)(idx4 + (size_t)(c >> 1) * N_ROWS + n0) = pack | (other << 4);
}

// ---------------- Kernel 2: lut fp32 -> bf16 (same [out][kdim] layout) ----------------
__global__ void k_cvt(const float* __restrict__ lut, unsigned short* __restrict__ lutb) {
    const int i = (blockIdx.x * blockDim.x + threadIdx.x) * 8;
    float4 a = *(const float4*)(lut + i);
    float4 b = *(const float4*)(lut + i + 4);
    uint4 o;
    o.x = f2bf(a.x) | (f2bf(a.y) << 16);
    o.y = f2bf(a.z) | (f2bf(a.w) << 16);
    o.z = f2bf(b.x) | (f2bf(b.y) << 16);
    o.w = f2bf(b.z) | (f2bf(b.w) << 16);
    *(uint4*)(lutb + i) = o;
}

// ---------------- Kernel 3: GEMM with implicit one-hot A (round-3 proven, 115us) ----------------
// out[n][k] = sum_c lut[k][c][idx[n][c]]
#define BM 128
#define BN 128
#define BKT 64          // kdim per LDS stage (2 MFMA K-steps of 32)
#define BSTAGE (BN * BKT * 2)   // 16 KB per B buffer
#define NT (KDIM / BKT)         // 64 tiles

template<bool STAGE_FP32>
__global__ __launch_bounds__(256, 4) void k_gemm(const unsigned short* __restrict__ lutb,
                                                 const float* __restrict__ lutf,
                                                 const unsigned char* __restrict__ idx4,
                                                 float* __restrict__ out) {
    __shared__ unsigned char smem[8192 + 2 * BSTAGE];    // idx 8KB + 2x B 16KB = 40 KB
    unsigned char* ish  = smem;                          // [cbp 64][row 128] (half window)
    unsigned char* bsh0 = smem + 8192;
    unsigned char* bsh1 = smem + 8192 + BSTAGE;

    const int t   = threadIdx.x;
    const int l15 = t & 15;
    const int q   = (t >> 4) & 3;          // quad within wave
    const int w   = t >> 6;
    const int wm  = w >> 1, wn = w & 1;    // 2x2 waves -> 64x64 tile each

    // XCD-column swizzle: each XCD owns 4 consecutive N-panels x all M-blocks.
    const int bid = blockIdx.x;
    const int bx  = ((bid & 7) << 2) | ((bid >> 3) & 3);   // n-block 0..31
    const int by  = bid >> 5;                              // m-block 0..31
    const int m0  = by * BM;
    const int n0  = bx * BN;

    // --- idx staging: half h covers cbp [h*64, h*64+64) x rows [m0, m0+128) ---
    auto stageIdx = [&](int h) {
        #pragma unroll
        for (int qq = 0; qq < 2; qq++) {
            int L = qq * 256 + t;          // 16B chunk: cbp = L>>3, row-part = L&7
            const unsigned char* g = idx4 + (size_t)(h * 64 + (L >> 3)) * N_ROWS + m0 + (L & 7) * 16;
            __builtin_amdgcn_global_load_lds(
                (const __attribute__((address_space(1))) void*)g,
                (__attribute__((address_space(3))) void*)(ish + L * 16), 16, 0, 0);
        }
    };

    // --- B tile staging: [128 out-rows][64 kdim] bf16, chunk-XOR swizzled ---
    auto stageB = [&](unsigned char* dst, int kbn) {
        #pragma unroll
        for (int qq = 0; qq < 4; qq++) {
            int L = qq * 256 + t;               // 16B chunk index in LDS
            int r = L >> 3, p = L & 7;
            int c = p ^ (r & 7);                // global chunk stored at position p
            const unsigned short* g = lutb + (size_t)(n0 + r) * KDIM + kbn + c * 8;
            __builtin_amdgcn_global_load_lds(
                (const __attribute__((address_space(1))) void*)g,
                (__attribute__((address_space(3))) void*)(dst + L * 16), 16, 0, 0);
        }
    };
    auto stageB32 = [&](unsigned char* dst, int kbn) {
        #pragma unroll
        for (int qq = 0; qq < 4; qq++) {
            int L = qq * 256 + t;
            int r = L >> 3, p = L & 7;
            int c = p ^ (r & 7);
            const float* g = lutf + (size_t)(n0 + r) * KDIM + kbn + c * 8;
            float4 f0 = *(const float4*)g;
            float4 f1 = *(const float4*)(g + 4);
            uint4 o;
            o.x = f2bf(f0.x) | (f2bf(f0.y) << 16);
            o.y = f2bf(f0.z) | (f2bf(f0.w) << 16);
            o.z = f2bf(f1.x) | (f2bf(f1.y) << 16);
            o.w = f2bf(f1.z) | (f2bf(f1.w) << 16);
            *(uint4*)(dst + L * 16) = o;
        }
    };

    f32x4 acc[4][4];
    #pragma unroll
    for (int mi = 0; mi < 4; mi++)
        #pragma unroll
        for (int ni = 0; ni < 4; ni++)
            acc[mi][ni] = (f32x4){0.f, 0.f, 0.f, 0.f};

    const int xorv = l15 & 7;                       // B chunk swizzle key
    const int bRowByte = (wn * 64 + l15) * (BKT * 2);
    const int aByte = wm * 64 + l15 * 4;            // idx word offset within a cbp row
    const int qh4  = (q >> 1) * 4;                  // nibble select: cb c0 vs c0+1
    const unsigned int sub8 = (q & 1) << 3;         // window offset within codebook

    // Upfront LDS->reg reads for both K-16 steps of a tile, then a pure-MFMA cluster.
    auto mfmaTile = [&](const unsigned char* src, int kb) {
        ABFrag bf2[2][4];
        unsigned int w32v[2];
        #pragma unroll
        for (int s = 0; s < 2; s++) {
            const int chunkOff = ((s * 4 + q) ^ xorv) * 16;
            #pragma unroll
            for (int ni = 0; ni < 4; ni++)
                bf2[s][ni].v = *(const bf16x8*)(src + bRowByte + ni * (16 * BKT * 2) + chunkOff);
            w32v[s] = *(const unsigned int*)(ish + ((((kb >> 5) + s) & 63) * 128) + aByte);
        }
        return [=](f32x4 (&ac)[4][4]) {
            #pragma unroll
            for (int s = 0; s < 2; s++) {
                ABFrag af[4];
                #pragma unroll
                for (int mi = 0; mi < 4; mi++) {
                    unsigned int T = (w32v[s] >> (mi * 8 + qh4)) & 0xFu;
                    unsigned int rel = T - sub8;                    // one-hot iff rel in [0,8)
                    unsigned long long sh = 0x3F80ull << ((rel & 3) << 4);  // bf16 1.0
                    af[mi].u[0] = (rel < 4u) ? sh : 0ull;
                    af[mi].u[1] = ((rel - 4u) < 4u) ? sh : 0ull;
                }
                #pragma unroll
                for (int mi = 0; mi < 4; mi++)
                    #pragma unroll
                    for (int ni = 0; ni < 4; ni++)
                        ac[mi][ni] = __builtin_amdgcn_mfma_f32_16x16x32_bf16(
                            af[mi].v, bf2[s][ni].v, ac[mi][ni], 0, 0, 0);
            }
        };
    };

    if (!STAGE_FP32) {
        // prologue: idx-half0(2) + stage0(4) + stage1(4) issued; vmcnt(4) -> idx half0
        // and stage0 complete, stage1's 4 still in flight.
        stageIdx(0);
        stageB(bsh0, 0);
        stageB(bsh1, BKT);
        asm volatile("s_waitcnt vmcnt(4)" ::: "memory");
        __builtin_amdgcn_s_barrier();
        __builtin_amdgcn_sched_barrier(0);

        unsigned char* cur = bsh0;
        unsigned char* nxt = bsh1;
        for (int tt = 0; tt < NT; tt++) {
            const int kb = tt * BKT;
            // [A] all LDS->reg reads for this tile
            auto doMfma = mfmaTile(cur, kb);
            asm volatile("s_waitcnt lgkmcnt(0)" ::: "memory");
            // [B] all waves done reading cur (and, at tt=31, ish half0) -> overwrite safe
            __builtin_amdgcn_s_barrier();
            __builtin_amdgcn_sched_barrier(0);
            // [C] restage: idx half1 (at tt=31, issued FIRST so vmcnt(4) at [E] covers it),
            //     then B tile tt+2 (issue only; no wait here)
            if (tt == 31) stageIdx(1);
            if (tt + 2 < NT) stageB(cur, kb + 2 * BKT);
            __builtin_amdgcn_sched_barrier(0);
            // [D] pure-MFMA cluster
            __builtin_amdgcn_s_setprio(1);
            doMfma(acc);
            __builtin_amdgcn_s_setprio(0);
            // [E] counted wait: tile tt+1's loads (and idx half1 at tt=31) done;
            //     tt+2's 4 newest stay in flight
            if (tt + 2 < NT) asm volatile("s_waitcnt vmcnt(4)" ::: "memory");
            else             asm volatile("s_waitcnt vmcnt(0)" ::: "memory");
            // [F] writes visible to all waves before next iteration reads
            __builtin_amdgcn_s_barrier();
            __builtin_amdgcn_sched_barrier(0);
            unsigned char* tmp = cur; cur = nxt; nxt = tmp;
        }
    } else {
        // Fallback (no workspace for lutb): single-buffer loop, convert on stage.
        stageIdx(0);
        asm volatile("s_waitcnt vmcnt(0)" ::: "memory");
        __syncthreads();
        for (int tt = 0; tt < NT; tt++) {
            const int kb = tt * BKT;
            if (tt == 32) stageIdx(1);          // prev sync: no readers of ish in flight
            stageB32(bsh0, kb);
            __syncthreads();                    // full drain covers global_load_lds too
            auto doMfma = mfmaTile(bsh0, kb);
            doMfma(acc);
            __syncthreads();
        }
    }

    // --- epilogue: MFMA row m = q*4 + r -> global row = m0 + wm*64 + 4*m + mi ---
    #pragma unroll
    for (int mi = 0; mi < 4; mi++) {
        #pragma unroll
        for (int ni = 0; ni < 4; ni++) {
            const int col = n0 + wn * 64 + ni * 16 + l15;
            #pragma unroll
            for (int r = 0; r < 4; r++) {
                const int row = m0 + wm * 64 + 4 * (q * 4 + r) + mi;
                out[(size_t)row * OUT_F + col] = acc[mi][ni][r];
            }
        }
    }
}

extern "C" void kernel_launch(void* const* d_in, const int* in_sizes, int n_in,
                              void* d_out, int out_size, void* d_ws, size_t ws_size,
                              hipStream_t stream) {
    const float* input = (const float*)d_in[0];
    const int*   dims  = (const int*)d_in[1];
    // d_in[2] selection_matrix, d_in[4] tree_des_mat: structure folded into the kernels
    const float* thr   = (const float*)d_in[3];
    const float* lut   = (const float*)d_in[5];
    float* out = (float*)d_out;

    const size_t lutbBytes = (size_t)OUT_F * KDIM * 2;       // 32 MB
    const size_t idxBytes  = (size_t)(C_CB / 2) * N_ROWS;    // 512 KB

    const int nblocks = (OUT_F / BN) * (N_ROWS / BM);        // 1024

    if (ws_size >= lutbBytes + idxBytes) {
        unsigned short* lutb = (unsigned short*)d_ws;
        unsigned char*  idx4 = (unsigned char*)d_ws + lutbBytes;
        k_idx<<<N_ROWS / IROWS, C_CB, 0, stream>>>(input, dims, thr, idx4);
        k_cvt<<<(OUT_F * KDIM) / (256 * 8), 256, 0, stream>>>(lut, lutb);
        k_gemm<false><<<nblocks, 256, 0, stream>>>(lutb, lut, idx4, out);
    } else {
        unsigned char* idx4 = (unsigned char*)d_ws;
        k_idx<<<N_ROWS / IROWS, C_CB, 0, stream>>>(input, dims, thr, idx4);
        k_gemm<true><<<nblocks, 256, 0, stream>>>(nullptr, lut, idx4, out);
    }
}

// Round 6
// 284.680 us; speedup vs baseline: 1.0875x; 1.0875x over previous
//
#include <hip/hip_runtime.h>

#define N_ROWS 4096
#define IN_F   4096
#define OUT_F  4096
#define C_CB   256
#define KDIM   4096   // C_CB * 16

typedef short bf16x8 __attribute__((ext_vector_type(8)));
typedef float f32x4  __attribute__((ext_vector_type(4)));

union ABFrag { unsigned long long u[2]; bf16x8 v; };

__device__ __forceinline__ unsigned int f2bf(float f) {
    unsigned int u = __builtin_bit_cast(unsigned int, f);
    return (u + 0x7FFFu + ((u >> 16) & 1u)) >> 16;   // RNE
}

// ---------------- Kernel 1: tree descent via LDS-staged gathers (R3 proven) ----------------
__global__ __launch_bounds__(256) void k_idx(const float* __restrict__ input,
                                             const int* __restrict__ dims,
                                             const float* __restrict__ thr,
                                             unsigned char* __restrict__ idx4) {
    __shared__ float rowS[IN_F];         // 16 KB
    __shared__ float thrS[C_CB * 15];    // 15 KB
    __shared__ int   dimS[C_CB * 4];     // 4 KB
    const int n = blockIdx.x;
    const int t = threadIdx.x;

    #pragma unroll
    for (int i = 0; i < 4; i++) dimS[i * 256 + t] = dims[i * 256 + t];
    #pragma unroll
    for (int i = 0; i < 15; i++) thrS[i * 256 + t] = thr[i * 256 + t];
    const float* row = input + (size_t)n * IN_F;
    #pragma unroll
    for (int i = 0; i < 4; i++) {
        float4 v = *(const float4*)(row + i * 1024 + t * 4);
        *(float4*)(rowS + i * 1024 + t * 4) = v;
    }
    __syncthreads();

    const int c = t;
    int4 d = *(const int4*)(dimS + c * 4);
    const float* th = thrS + c * 15;
    float x0 = rowS[d.x], x1 = rowS[d.y], x2 = rowS[d.z], x3 = rowS[d.w];
    int b0 = x0 > th[0];
    int j1 = 1 + b0;
    int b1 = x1 > th[j1];
    int j2 = 2 * j1 + 1 + b1;
    int b2 = x2 > th[j2];
    int j3 = 2 * j2 + 1 + b2;
    int b3 = x3 > th[j3];
    int idx = (b0 << 3) | (b1 << 2) | (b2 << 1) | b3;
    int other = __shfl_xor(idx, 1);
    if (!(c & 1))
        idx4[(c >> 1) * N_ROWS + n] = (unsigned char)(idx | (other << 4));
}

// ---------------- Kernel 2: lut fp32 -> bf16 (same [out][kdim] layout) ----------------
__global__ void k_cvt(const float* __restrict__ lut, unsigned short* __restrict__ lutb) {
    const int i = (blockIdx.x * blockDim.x + threadIdx.x) * 8;
    float4 a = *(const float4*)(lut + i);
    float4 b = *(const float4*)(lut + i + 4);
    uint4 o;
    o.x = f2bf(a.x) | (f2bf(a.y) << 16);
    o.y = f2bf(a.z) | (f2bf(a.w) << 16);
    o.z = f2bf(b.x) | (f2bf(b.y) << 16);
    o.w = f2bf(b.z) | (f2bf(b.w) << 16);
    *(uint4*)(lutb + i) = o;
}

// ---------------- Kernel 3: GEMM with implicit one-hot A ----------------
// out[n][k] = sum_c lut[k][c][idx[n][c]]
// Wave-tile 64x128 (ni=8, R1-verified geometry): A-build VALU per MFMA halved.
// Phase-split schedule: s1 ds_reads issued BEFORE s0's MFMA cluster (complete
// under it), barrier mid-tile, restage, s1 cluster. Counted vmcnt(8), never 0
// in-loop (R2/R3 proven discipline).
#define BM 128
#define BN 256
#define BKT 64          // kdim per LDS stage (2 MFMA K-steps of 32)
#define BSTAGE (BN * BKT * 2)   // 32 KB per B buffer
#define NT (KDIM / BKT)         // 64 tiles

template<bool STAGE_FP32>
__global__ __launch_bounds__(256, 2) void k_gemm(const unsigned short* __restrict__ lutb,
                                                 const float* __restrict__ lutf,
                                                 const unsigned char* __restrict__ idx4,
                                                 float* __restrict__ out) {
    __shared__ unsigned char smem[8192 + 2 * BSTAGE];    // idx 8KB + 2x B 32KB = 72 KB
    unsigned char* ish  = smem;                          // [cbp 64][row 128] (half window)
    unsigned char* bsh0 = smem + 8192;
    unsigned char* bsh1 = smem + 8192 + BSTAGE;

    const int t   = threadIdx.x;
    const int l15 = t & 15;
    const int q   = (t >> 4) & 3;          // quad within wave
    const int w   = t >> 6;
    const int wm  = w >> 1, wn = w & 1;    // 2x2 waves -> 64x128 tile each

    // XCD swizzle: XCD = bid&7 owns 2 consecutive n-panels x all 32 m-blocks.
    const int bid = blockIdx.x;            // 512 blocks = 16 bx x 32 by
    const int bx  = ((bid & 7) << 1) | ((bid >> 3) & 1);   // n-block 0..15
    const int by  = bid >> 4;                              // m-block 0..31
    const int m0  = by * BM;
    const int n0  = bx * BN;

    // --- idx staging: half h covers cbp [h*64, h*64+64) x rows [m0, m0+128) ---
    auto stageIdx = [&](int h) {
        #pragma unroll
        for (int qq = 0; qq < 2; qq++) {
            int L = qq * 256 + t;          // 16B chunk: cbp = L>>3, row-part = L&7
            const unsigned char* g = idx4 + (size_t)(h * 64 + (L >> 3)) * N_ROWS + m0 + (L & 7) * 16;
            __builtin_amdgcn_global_load_lds(
                (const __attribute__((address_space(1))) void*)g,
                (__attribute__((address_space(3))) void*)(ish + L * 16), 16, 0, 0);
        }
    };

    // --- B tile staging: [256 out-rows][64 kdim] bf16, chunk-XOR swizzled ---
    auto stageB = [&](unsigned char* dst, int kbn) {
        #pragma unroll
        for (int qq = 0; qq < 8; qq++) {
            int L = qq * 256 + t;               // 16B chunk index in LDS
            int r = L >> 3, p = L & 7;
            int c = p ^ (r & 7);                // global chunk stored at position p
            const unsigned short* g = lutb + (size_t)(n0 + r) * KDIM + kbn + c * 8;
            __builtin_amdgcn_global_load_lds(
                (const __attribute__((address_space(1))) void*)g,
                (__attribute__((address_space(3))) void*)(dst + L * 16), 16, 0, 0);
        }
    };
    auto stageB32 = [&](unsigned char* dst, int kbn) {
        #pragma unroll
        for (int qq = 0; qq < 8; qq++) {
            int L = qq * 256 + t;
            int r = L >> 3, p = L & 7;
            int c = p ^ (r & 7);
            const float* g = lutf + (size_t)(n0 + r) * KDIM + kbn + c * 8;
            float4 f0 = *(const float4*)g;
            float4 f1 = *(const float4*)(g + 4);
            uint4 o;
            o.x = f2bf(f0.x) | (f2bf(f0.y) << 16);
            o.y = f2bf(f0.z) | (f2bf(f0.w) << 16);
            o.z = f2bf(f1.x) | (f2bf(f1.y) << 16);
            o.w = f2bf(f1.z) | (f2bf(f1.w) << 16);
            *(uint4*)(dst + L * 16) = o;
        }
    };

    f32x4 acc[4][8];
    #pragma unroll
    for (int mi = 0; mi < 4; mi++)
        #pragma unroll
        for (int ni = 0; ni < 8; ni++)
            acc[mi][ni] = (f32x4){0.f, 0.f, 0.f, 0.f};

    const int xorv = l15 & 7;                       // B chunk swizzle key
    const int bRowByte = (wn * 128 + l15) * (BKT * 2);
    const int aByte = wm * 64 + l15 * 4;            // idx word offset within a cbp row
    const int qh4  = (q >> 1) * 4;                  // nibble select: cb c0 vs c0+1
    const unsigned int sub8 = (q & 1) << 3;         // window offset within codebook

    // per-phase LDS->reg reads (8 x ds_read_b128 + 1 x b32)
    auto readPhase = [&](const unsigned char* src, int s, int kb, ABFrag (&bf)[8], unsigned int& w32) {
        const int chunkOff = ((s * 4 + q) ^ xorv) * 16;
        #pragma unroll
        for (int ni = 0; ni < 8; ni++)
            bf[ni].v = *(const bf16x8*)(src + bRowByte + ni * (16 * BKT * 2) + chunkOff);
        w32 = *(const unsigned int*)(ish + ((((kb >> 5) + s) & 63) * 128) + aByte);
    };
    // per-phase MFMA cluster: build 4 one-hot A frags, 32 MFMAs
    auto mfmaPhase = [&](const ABFrag (&bf)[8], unsigned int w32) {
        ABFrag af[4];
        #pragma unroll
        for (int mi = 0; mi < 4; mi++) {
            unsigned int T = (w32 >> (mi * 8 + qh4)) & 0xFu;
            unsigned int rel = T - sub8;                    // one-hot iff rel in [0,8)
            unsigned long long sh = 0x3F80ull << ((rel & 3) << 4);  // bf16 1.0
            af[mi].u[0] = (rel < 4u) ? sh : 0ull;
            af[mi].u[1] = ((rel - 4u) < 4u) ? sh : 0ull;
        }
        #pragma unroll
        for (int mi = 0; mi < 4; mi++)
            #pragma unroll
            for (int ni = 0; ni < 8; ni++)
                acc[mi][ni] = __builtin_amdgcn_mfma_f32_16x16x32_bf16(
                    af[mi].v, bf[ni].v, acc[mi][ni], 0, 0, 0);
    };

    if (!STAGE_FP32) {
        // prologue: idx-half0(2) + stage0(8) + stage1(8); vmcnt(8) -> idx half0 and
        // stage0 complete, stage1's 8 still in flight.
        stageIdx(0);
        stageB(bsh0, 0);
        stageB(bsh1, BKT);
        asm volatile("s_waitcnt vmcnt(8)" ::: "memory");
        __builtin_amdgcn_s_barrier();
        __builtin_amdgcn_sched_barrier(0);

        unsigned char* cur = bsh0;
        unsigned char* nxt = bsh1;
        ABFrag bf0[8], bf1[8];
        unsigned int w0, w1;
        for (int tt = 0; tt < NT; tt++) {
            const int kb = tt * BKT;
            // [A0] s=0 reads
            readPhase(cur, 0, kb, bf0, w0);
            asm volatile("s_waitcnt lgkmcnt(0)" ::: "memory");
            __builtin_amdgcn_sched_barrier(0);
            // [D0] issue s=1 reads (no wait), then s=0 MFMA cluster over them
            readPhase(cur, 1, kb, bf1, w1);
            __builtin_amdgcn_sched_barrier(0);
            __builtin_amdgcn_s_setprio(1);
            mfmaPhase(bf0, w0);
            __builtin_amdgcn_s_setprio(0);
            asm volatile("s_waitcnt lgkmcnt(0)" ::: "memory");
            __builtin_amdgcn_sched_barrier(0);
            // [B] all waves done reading cur (and, at tt=31, ish half0) -> overwrite safe
            __builtin_amdgcn_s_barrier();
            __builtin_amdgcn_sched_barrier(0);
            // [C] restage: idx half1 (tt=31, issued FIRST so vmcnt(8) at [E] covers it),
            //     then B tile tt+2 (issue only)
            if (tt == 31) stageIdx(1);
            if (tt + 2 < NT) stageB(cur, kb + 2 * BKT);
            __builtin_amdgcn_sched_barrier(0);
            // [D1] s=1 MFMA cluster (stage loads fly underneath)
            __builtin_amdgcn_s_setprio(1);
            mfmaPhase(bf1, w1);
            __builtin_amdgcn_s_setprio(0);
            // [E] counted wait: tile tt+1's 8 loads (and idx half1 at tt=31) done;
            //     tt+2's 8 newest stay in flight
            if (tt + 2 < NT) asm volatile("s_waitcnt vmcnt(8)" ::: "memory");
            else             asm volatile("s_waitcnt vmcnt(0)" ::: "memory");
            // [F] writes visible to all waves before next iteration reads
            __builtin_amdgcn_s_barrier();
            __builtin_amdgcn_sched_barrier(0);
            unsigned char* tmp = cur; cur = nxt; nxt = tmp;
        }
    } else {
        // Fallback (no workspace for lutb): single-buffer loop, convert on stage.
        stageIdx(0);
        asm volatile("s_waitcnt vmcnt(0)" ::: "memory");
        __syncthreads();
        ABFrag bfx[8];
        unsigned int wx;
        for (int tt = 0; tt < NT; tt++) {
            const int kb = tt * BKT;
            if (tt == 32) stageIdx(1);          // prev sync: no readers of ish in flight
            stageB32(bsh0, kb);
            __syncthreads();                    // full drain covers global_load_lds too
            #pragma unroll
            for (int s = 0; s < 2; s++) {
                readPhase(bsh0, s, kb, bfx, wx);
                mfmaPhase(bfx, wx);
            }
            __syncthreads();
        }
    }

    // --- epilogue: MFMA row m = q*4 + r -> global row = m0 + wm*64 + 4*m + mi ---
    #pragma unroll
    for (int mi = 0; mi < 4; mi++) {
        #pragma unroll
        for (int ni = 0; ni < 8; ni++) {
            const int col = n0 + wn * 128 + ni * 16 + l15;
            #pragma unroll
            for (int r = 0; r < 4; r++) {
                const int row = m0 + wm * 64 + 4 * (q * 4 + r) + mi;
                out[(size_t)row * OUT_F + col] = acc[mi][ni][r];
            }
        }
    }
}

extern "C" void kernel_launch(void* const* d_in, const int* in_sizes, int n_in,
                              void* d_out, int out_size, void* d_ws, size_t ws_size,
                              hipStream_t stream) {
    const float* input = (const float*)d_in[0];
    const int*   dims  = (const int*)d_in[1];
    // d_in[2] selection_matrix, d_in[4] tree_des_mat: structure folded into the kernels
    const float* thr   = (const float*)d_in[3];
    const float* lut   = (const float*)d_in[5];
    float* out = (float*)d_out;

    const size_t lutbBytes = (size_t)OUT_F * KDIM * 2;       // 32 MB
    const size_t idxBytes  = (size_t)(C_CB / 2) * N_ROWS;    // 512 KB

    const int nblocks = (OUT_F / BN) * (N_ROWS / BM);        // 16 x 32 = 512

    if (ws_size >= lutbBytes + idxBytes) {
        unsigned short* lutb = (unsigned short*)d_ws;
        unsigned char*  idx4 = (unsigned char*)d_ws + lutbBytes;
        k_idx<<<N_ROWS, C_CB, 0, stream>>>(input, dims, thr, idx4);
        k_cvt<<<(OUT_F * KDIM) / (256 * 8), 256, 0, stream>>>(lut, lutb);
        k_gemm<false><<<nblocks, 256, 0, stream>>>(lutb, lut, idx4, out);
    } else {
        unsigned char* idx4 = (unsigned char*)d_ws;
        k_idx<<<N_ROWS, C_CB, 0, stream>>>(input, dims, thr, idx4);
        k_gemm<true><<<nblocks, 256, 0, stream>>>(nullptr, lut, idx4, out);
    }
}